// Round 5
// baseline (313.555 us; speedup 1.0000x reference)
//
#include <hip/hip_runtime.h>
#include <stdint.h>

// Problem dims (fixed by setup_inputs)
#define M_TOTAL 2048     // B (feats rows)
#define N_TOTAL 16384    // Bs*TOPK (support rows)
#define K_TOTAL 2048     // C
#define NPARTS  256      // 64 n-tiles * 4 n-waves
#define NT      (K_TOTAL / 128)   // 16 K-tiles

// Uniform MX scale: stored_fp8 = value * 2^9, HW dequant scale = 2^-9 per operand.
#define SCALE_E8M0 0x76767676
#define SCALE_F 512.0f

typedef __attribute__((ext_vector_type(4))) int   int4v;    // 16B (one ds_read_b128)
typedef __attribute__((ext_vector_type(8))) int   int8v;    // 32B fp8 MFMA A/B frag
typedef __attribute__((ext_vector_type(4))) float floatx4;  // MFMA C/D frag

// ---------------------------------------------------------------- fp32 -> fp8 e4m3 (scaled)
__device__ __forceinline__ uint32_t pack8(float4 v) {
    int p = __builtin_amdgcn_cvt_pk_fp8_f32(v.x * SCALE_F, v.y * SCALE_F, 0, 0);
    p = __builtin_amdgcn_cvt_pk_fp8_f32(v.z * SCALE_F, v.w * SCALE_F, p, 1);
    return (uint32_t)p;
}

__device__ __forceinline__ void cvt_loop16(const float4* __restrict__ src,
                                           uint4* __restrict__ dst,
                                           int i, int stride, int n16) {
    for (; i < n16; i += stride) {
        const float4* p = src + (size_t)i * 4;
        uint4 o;
        o.x = pack8(p[0]);
        o.y = pack8(p[1]);
        o.z = pack8(p[2]);
        o.w = pack8(p[3]);
        dst[i] = o;
    }
}

__global__ __launch_bounds__(256) void cvt_fp8_all(
        const float4* __restrict__ a, const float4* __restrict__ b,
        uint4* __restrict__ oa, uint4* __restrict__ ob) {
    if (blockIdx.x < 512)
        cvt_loop16(a, oa, blockIdx.x * 256 + threadIdx.x, 512 * 256,
                   M_TOTAL * K_TOTAL / 16);
    else
        cvt_loop16(b, ob, (blockIdx.x - 512) * 256 + threadIdx.x, 2048 * 256,
                   N_TOTAL * K_TOTAL / 16);
}

// ---------------------------------------------------------------- GEMM + fused epilogue
__device__ __forceinline__ void load16(const void* g, void* l) {
    __builtin_amdgcn_global_load_lds(
        (const __attribute__((address_space(1))) void*)g,
        (__attribute__((address_space(3))) void*)l, 16, 0, 0);
}

__device__ __forceinline__ int8v frag8(const char* lo_p, const char* hi_p) {
    int4v lo = *(const int4v*)lo_p;
    int4v hi = *(const int4v*)hi_p;
    return (int8v){lo.x, lo.y, lo.z, lo.w, hi.x, hi.y, hi.z, hi.w};
}

// ===== 256x256 / 8 waves / dbuf LDS — faithful m201-style derived-waits port.
// Round-4 (one-phase-ahead lgkm(4) + stage bursts + vmcnt(0)) measured 7650
// cy/tile vs ~2260 floor (MfmaUtil 26%). This version uses the template's
// discipline exactly:
//   per tile T (buf b = T&1), 4 phases, each:
//     { ds_reads for THIS phase | stage 1 half-tile of T+1 | BAR | lgkm(0) |
//       setprio(1) | 8 MFMA | setprio(0) | BAR }
//     ph1 reads B0-3 + A0,A1 (12 rd); ph2: A2,A3; ph3: A4,A5; ph4: A6,A7 (no
//     stage slot). Overlap comes from inter-wave stagger: reads issue before
//     the BAR, early-serviced waves MFMA while late waves drain; setprio
//     arbitrates (T5 role-split).
//   per-tile boundary (the ONLY vmem wait, counted, never 0 mid-loop):
//     { stage (T+2).h0 -> buf b (freed: all waves' lgkm(0) preceded ph4's end
//       BAR) | vmcnt(2) [outstanding = T+1's 8 + these 2 -> forces T+1 fully
//       landed, 2 fly] | BAR = publish T+1 }
// Stage slots for tile X: h0 at boundary entering X-1, h1/h2/h3 at ph1-3 of
// X-1. Tail: boundary after T=14 has nothing new to stage -> vmcnt(0) once.
// All barriers wave-uniform; stages into a buffer always follow the BAR after
// its readers' lgkm(0) drain.
// Swizzle (verified rounds 0-4, absmax 0): 16B chunk q of row R at phys
// q ^ (R&7), applied on the GLOBAL side of global_load_lds; LDS dest linear.
__global__ __launch_bounds__(512, 2) void gemm_lp(
        const char* __restrict__ Af8, const char* __restrict__ Bf8,
        const int* __restrict__ labels, const int* __restrict__ labels_s,
        float* __restrict__ pminp, float* __restrict__ psump) {
    __shared__ __align__(16) char smA[2][256][128];   // 64 KiB
    __shared__ __align__(16) char smB[2][256][128];   // 64 KiB
    __shared__ int lab_m[256];
    __shared__ int lab_n[256];

    const int t    = threadIdx.x;
    const int lane = t & 63;
    const int wave = t >> 6;      // 0..7
    const int wm   = wave >> 2;   // row half   (0..1) -> 128 rows
    const int wn   = wave & 3;    // col quarter(0..3) -> 64 cols
    const int m0   = blockIdx.y * 256;
    const int n0   = blockIdx.x * 256;

    if (t < 256) lab_m[t] = labels[m0 + t];
    else         lab_n[t - 256] = labels_s[n0 + t - 256];

    // staging geometry: round j (0..3) covers rows j*64 + (t>>3); phys chunk t&7
    // -> global k-chunk q = (t&7) ^ ((t>>3)&7)   (row&7 is j-independent).
    const int rq = t >> 3;                                  // 0..63
    const int qt = (t & 7) ^ ((t >> 3) & 7);
    const char* aG = Af8 + (long)(m0 + rq) * K_TOTAL + qt * 16;
    const char* bG = Bf8 + (long)(n0 + rq) * K_TOTAL + qt * 16;
    const int ldst = wave * 1024;            // wave-uniform LDS base; HW adds lane*16B

#define STAGE_A(T, J) load16(aG + (T) * 128 + (J) * 64 * K_TOTAL, \
                             &smA[(T) & 1][(J) * 64][0] + ldst)
#define STAGE_B(T, J) load16(bG + (T) * 128 + (J) * 64 * K_TOTAL, \
                             &smB[(T) & 1][(J) * 64][0] + ldst)
// half-tiles: h0 = A rows 0-127, h1 = A rows 128-255, h2 = B rows 0-127,
// h3 = B rows 128-255; each = 2 gloads/thread (16 KB).
#define STAGE_H(T, H)                                                          \
    do {                                                                       \
        if ((H) < 2) { STAGE_A(T, (H) * 2); STAGE_A(T, (H) * 2 + 1); }         \
        else { STAGE_B(T, ((H) - 2) * 2); STAGE_B(T, ((H) - 2) * 2 + 1); }     \
    } while (0)

    // Fragment bases: row R = base + lcol (+ mi*16 via 2048B immediates),
    // k-chunks {2q, 2q+1} at phys (k ^ (lcol&7)).
    const int quad = lane >> 4;
    const int lcol = lane & 15;
    const int plo = ((2 * quad)     ^ (lcol & 7)) << 4;
    const int phi = ((2 * quad + 1) ^ (lcol & 7)) << 4;
    const char* aF = &smA[0][wm * 128 + lcol][0];
    const char* bF = &smB[0][wn * 64  + lcol][0];

#define RD(P) frag8((P) + plo, (P) + phi)

    floatx4 acc[8][4];
#pragma unroll
    for (int mi = 0; mi < 8; ++mi)
#pragma unroll
        for (int ni = 0; ni < 4; ++ni)
            acc[mi][ni] = (floatx4){0.f, 0.f, 0.f, 0.f};

    int8v bv[4];

#define MFMA_PAIR(R, AV0, AV1)                                                 \
    do {                                                                       \
        _Pragma("unroll")                                                      \
        for (int ni = 0; ni < 4; ++ni) {                                       \
            acc[R][ni] = __builtin_amdgcn_mfma_scale_f32_16x16x128_f8f6f4(     \
                AV0, bv[ni], acc[R][ni], 0, 0, 0, SCALE_E8M0, 0, SCALE_E8M0);  \
            acc[R + 1][ni] = __builtin_amdgcn_mfma_scale_f32_16x16x128_f8f6f4( \
                AV1, bv[ni], acc[R + 1][ni], 0, 0, 0, SCALE_E8M0, 0,           \
                SCALE_E8M0);                                                   \
        }                                                                      \
    } while (0)

#define PHASE_TAIL(R, AV0, AV1)                                                \
    __builtin_amdgcn_s_barrier();                                              \
    asm volatile("s_waitcnt lgkmcnt(0)" ::: "memory");                         \
    __builtin_amdgcn_s_setprio(1);                                             \
    MFMA_PAIR(R, AV0, AV1);                                                    \
    __builtin_amdgcn_s_setprio(0);                                             \
    __builtin_amdgcn_s_barrier();

    // Prologue: tile0 fully + tile1.h0; counted boundary wait; publish T0.
    STAGE_H(0, 0); STAGE_H(0, 1); STAGE_H(0, 2); STAGE_H(0, 3);
    STAGE_H(1, 0);
    asm volatile("s_waitcnt vmcnt(2)" ::: "memory");
    __builtin_amdgcn_s_barrier();

#pragma unroll 1
    for (int T = 0; T < NT; ++T) {
        const char* aB = aF + (T & 1) * 32768;
        const char* bB = bF + (T & 1) * 32768;
        const bool s1 = (T + 1 < NT);

        // ---- ph1: B0-3 + A0,A1 (12 reads); stage (T+1).h1
        bv[0] = RD(bB + 0 * 2048);
        bv[1] = RD(bB + 1 * 2048);
        bv[2] = RD(bB + 2 * 2048);
        bv[3] = RD(bB + 3 * 2048);
        int8v a0 = RD(aB + 0 * 2048), a1 = RD(aB + 1 * 2048);
        if (s1) STAGE_H(T + 1, 1);
        PHASE_TAIL(0, a0, a1)

        // ---- ph2: A2,A3; stage (T+1).h2
        int8v a2 = RD(aB + 2 * 2048), a3 = RD(aB + 3 * 2048);
        if (s1) STAGE_H(T + 1, 2);
        PHASE_TAIL(2, a2, a3)

        // ---- ph3: A4,A5; stage (T+1).h3
        int8v a4 = RD(aB + 4 * 2048), a5 = RD(aB + 5 * 2048);
        if (s1) STAGE_H(T + 1, 3);
        PHASE_TAIL(4, a4, a5)

        // ---- ph4: A6,A7 (no stage slot)
        int8v a6 = RD(aB + 6 * 2048), a7 = RD(aB + 7 * 2048);
        PHASE_TAIL(6, a6, a7)
        // after this BAR: every wave's lgkm(0) has drained -> buf (T&1) free

        // ---- boundary: stage (T+2).h0 into freed buf; counted wait; publish T+1
        if (T + 2 < NT) {
            STAGE_H(T + 2, 0);
            asm volatile("s_waitcnt vmcnt(2)" ::: "memory");
            __builtin_amdgcn_s_barrier();
        } else if (T + 1 < NT) {
            asm volatile("s_waitcnt vmcnt(0)" ::: "memory");   // once, at the tail
            __builtin_amdgcn_s_barrier();
        }
    }
#undef PHASE_TAIL
#undef MFMA_PAIR
#undef RD
#undef STAGE_H
#undef STAGE_A
#undef STAGE_B

    // Epilogue: e = exp(sim/TEMP) = exp2(sim * 28.8539); masked min/sum over cols.
    // C/D layout (shape-determined): col = lane&15, row = quad*4 + reg
    const float scale = 28.853900817779268f;     // 20 * log2(e)
#pragma unroll
    for (int mi = 0; mi < 8; ++mi) {
#pragma unroll
        for (int r = 0; r < 4; ++r) {
            const int row_local = wm * 128 + mi * 16 + quad * 4 + r;
            const int lab = lab_m[row_local];
            float minv = __builtin_inff();
            float sumv = 0.f;
#pragma unroll
            for (int ni = 0; ni < 4; ++ni) {
                const int col_local = wn * 64 + ni * 16 + lcol;
                const float e = exp2f(acc[mi][ni][r] * scale);
                const bool pos = (lab_n[col_local] == lab);
                minv = pos ? fminf(minv, e) : minv;
                sumv = pos ? sumv : (sumv + e);
            }
#pragma unroll
            for (int off = 1; off < 16; off <<= 1) {
                minv = fminf(minv, __shfl_xor(minv, off, 16));
                sumv += __shfl_xor(sumv, off, 16);
            }
            if (lcol == 0) {
                // partials laid out [row][part] so reduce_rows reads coalesced
                const long idx = (long)(m0 + row_local) * NPARTS + blockIdx.x * 4 + wn;
                pminp[idx] = minv;
                psump[idx] = sumv;
            }
        }
    }
}

// ---------------------------------------------------------------- row fold + mean
__global__ __launch_bounds__(256) void reduce_rows(
        const float* __restrict__ pminp, const float* __restrict__ psump,
        float* __restrict__ loss) {
    const int row  = blockIdx.x * 4 + (threadIdx.x >> 6);
    const int lane = threadIdx.x & 63;
    float m = __builtin_inff();
    float s = 0.f;
#pragma unroll
    for (int k = 0; k < NPARTS / 64; ++k) {
        const long j = (long)row * NPARTS + lane + k * 64;
        m = fminf(m, pminp[j]);
        s += psump[j];
    }
#pragma unroll
    for (int off = 1; off < 64; off <<= 1) {
        m = fminf(m, __shfl_xor(m, off, 64));
        s += __shfl_xor(s, off, 64);
    }
    if (lane == 0) loss[row] = -logf(m / (m + s + 1e-6f) + 1e-6f);
}

__global__ void final_mean(const float* __restrict__ loss, float* __restrict__ out) {
    float s = 0.f;
    for (int i = threadIdx.x; i < M_TOTAL; i += 256) s += loss[i];
#pragma unroll
    for (int off = 32; off > 0; off >>= 1) s += __shfl_xor(s, off, 64);
    __shared__ float wsum[4];
    if ((threadIdx.x & 63) == 0) wsum[threadIdx.x >> 6] = s;
    __syncthreads();
    if (threadIdx.x == 0)
        out[0] = (wsum[0] + wsum[1] + wsum[2] + wsum[3]) * (1.0f / (float)M_TOTAL);
}

// ---------------------------------------------------------------- launcher
extern "C" void kernel_launch(void* const* d_in, const int* in_sizes, int n_in,
                              void* d_out, int out_size, void* d_ws, size_t ws_size,
                              hipStream_t stream) {
    const float* feats    = (const float*)d_in[0];
    const float* feats_s  = (const float*)d_in[1];
    const int*   labels   = (const int*)d_in[2];
    const int*   labels_s = (const int*)d_in[3];
    float*       out      = (float*)d_out;

    char* ws = (char*)d_ws;
    char*  Af8   = ws;                                    //  4,194,304 B
    char*  Bf8   = ws + 4194304;                          // 33,554,432 B
    float* pminp = (float*)(ws + 37748736);               //  2,097,152 B
    float* psump = (float*)(ws + 39845888);               //  2,097,152 B
    float* loss  = (float*)(ws + 41943040);               //      8,192 B

    cvt_fp8_all<<<2560, 256, 0, stream>>>((const float4*)feats, (const float4*)feats_s,
                                          (uint4*)Af8, (uint4*)Bf8);

    dim3 grid(N_TOTAL / 256, M_TOTAL / 256);              // 64 x 8
    gemm_lp<<<grid, 512, 0, stream>>>(Af8, Bf8, labels, labels_s, pminp, psump);

    reduce_rows<<<512, 256, 0, stream>>>(pminp, psump, loss);
    final_mean<<<1, 256, 0, stream>>>(loss, out);
}

// Round 6
// 296.942 us; speedup vs baseline: 1.0559x; 1.0559x over previous
//
#include <hip/hip_runtime.h>
#include <hip/hip_bf16.h>
#include <stdint.h>

// Problem dims (fixed by setup_inputs)
#define M_TOTAL 2048     // B (feats rows)
#define N_TOTAL 16384    // Bs*TOPK (support rows)
#define K_TOTAL 2048     // C
#define NPARTS  256      // 128 n-tiles * 2 n-waves

// Uniform MX scale: stored_fp8 = value * 2^9, HW dequant scale = 2^-9 per operand.
// e8m0 byte = 127 - 9 = 118 = 0x76. Uniform bytes -> immune to scale-lane layout.
#define SCALE_E8M0 0x76767676
#define SCALE_F 512.0f

typedef __attribute__((ext_vector_type(4))) int   int4v;    // 16B (one ds_read_b128)
typedef __attribute__((ext_vector_type(8))) int   int8v;    // 32B fp8 MFMA A/B frag
typedef __attribute__((ext_vector_type(4))) float floatx4;  // MFMA C/D frag

// ---------------------------------------------------------------- fp32 -> fp8 e4m3 (scaled)
__device__ __forceinline__ void cvt_loop(const float4* __restrict__ src,
                                         uint32_t* __restrict__ dst,
                                         int i, int stride, int n4) {
    for (; i < n4; i += stride) {
        float4 v = src[i];
        int p = __builtin_amdgcn_cvt_pk_fp8_f32(v.x * SCALE_F, v.y * SCALE_F, 0, 0);
        p = __builtin_amdgcn_cvt_pk_fp8_f32(v.z * SCALE_F, v.w * SCALE_F, p, 1);
        dst[i] = (uint32_t)p;
    }
}

// one launch for both arrays: blocks [0,512) -> A, [512,2560) -> B (uniform branch)
// Also zeroes the loss accumulator (out) -- stream order guarantees it precedes
// reduce_fused's atomicAdds (3 kernels later), no memset node needed.
__global__ void cvt_fp8_all(const float4* __restrict__ a, const float4* __restrict__ b,
                            uint32_t* __restrict__ oa, uint32_t* __restrict__ ob,
                            float* __restrict__ out) {
    if (blockIdx.x == 0 && threadIdx.x == 0) out[0] = 0.f;
    if (blockIdx.x < 512)
        cvt_loop(a, oa, blockIdx.x * 256 + threadIdx.x, 512 * 256,
                 M_TOTAL * K_TOTAL / 4);
    else
        cvt_loop(b, ob, (blockIdx.x - 512) * 256 + threadIdx.x, 2048 * 256,
                 N_TOTAL * K_TOTAL / 4);
}

// ---------------------------------------------------------------- GEMM + fused epilogue
__device__ __forceinline__ void load16(const void* g, void* l) {
    __builtin_amdgcn_global_load_lds(
        (const __attribute__((address_space(1))) void*)g,
        (__attribute__((address_space(3))) void*)l, 16, 0, 0);
}

// ===== Measured-optimum structure (round 0 of this session / round 5 of the
// previous: gemm 86 us, ~1590 TF = 96% of the m148 MX-fp8 2-barrier plateau,
// MfmaUtil 34%). Variants measured and REJECTED:
//   - 256^2 8-wave coarse counted-vmcnt (R1): 101 us, MfmaUtil 28%.
//   - 256^2 fine 4-phase, one-phase-ahead lgkm(4) (R3 spilled: 132 us;
//     R4 de-spilled: 102 us, MfmaUtil 26%).
//   - 256^2 m201-style per-phase stage+lgkm(0)+counted-vmcnt boundary (R5):
//     107 us, MfmaUtil 25%.
//   Root cause common to all three: 133 KB LDS -> 1 block/CU -> barriers stall
//   the whole CU, no cross-block overlap; ds_read floor (~2300 cy/tile/CU)
//   == MFMA floor -> lockstep phases serialize what 2.2-blocks/CU of this
//   128^2 kernel overlap naturally. Family falsified for this MX-fp8 problem.
//   Earlier session also rejected: dbuf single-barrier (105 us), BK=256
//   (93 us), full K-unroll (196 us, spills).
//
// LDS tile: 128 rows x 128 B (K=128 fp8), single-buffered. 16B chunk at global
// k-pos q of row R lives at phys pos p = q ^ (R & 7). Fragment loads are two
// ds_read_b128 per 32B operand; quarter-wave lanes (R&7 = lcol&7) spread over
// all 8 bank-groups -> 2-way aliasing (free per m136; shows as a benign
// ~8.4M SQ_LDS_BANK_CONFLICT count). Swizzle applied on the GLOBAL address
// side of global_load_lds (LDS dest must remain wave-base + lane*16B).
__global__ __launch_bounds__(256) void gemm_lp(
        const char* __restrict__ Af8, const char* __restrict__ Bf8,
        const int* __restrict__ labels, const int* __restrict__ labels_s,
        float* __restrict__ pminp, float* __restrict__ psump) {
    __shared__ __align__(16) char lsA[128 * 128];
    __shared__ __align__(16) char lsB[128 * 128];
    __shared__ int lab_m[128];
    __shared__ int lab_n[128];

    const int t    = threadIdx.x;
    const int lane = t & 63;
    const int wave = t >> 6;
    const int wm   = wave >> 1;   // row half (0..1)
    const int wn   = wave & 1;    // col half (0..1)
    const int m0   = blockIdx.y * 128;
    const int n0   = blockIdx.x * 128;

    if (t < 128) lab_m[t] = labels[m0 + t];
    else         lab_n[t - 128] = labels_s[n0 + t - 128];

    // staging: issue j (0..3) per matrix; thread t fills phys chunk c = j*256+t.
    // phys row = j*32 + (t>>3), phys pos = t&7  ->  global 16B k-chunk
    // q = (t&7) ^ ((t>>3)&7)   (row&7 = (t>>3)&7, j-independent).
    const int rq = t >> 3;                                  // row within 32-row group
    const int qt = (t & 7) ^ ((t >> 3) & 7);                // swizzled k-chunk
    const char* aPtr = Af8 + (long)(m0 + rq) * K_TOTAL + qt * 16;
    const char* bPtr = Bf8 + (long)(n0 + rq) * K_TOTAL + qt * 16;
    char* lA = lsA + wave * 1024;            // wave-uniform LDS base; HW adds lane*16B
    char* lB = lsB + wave * 1024;

    // Fragment bases: row R = (wm|wn)*64 + lcol (+ mi*16), k-chunks {2q,2q+1} at
    // phys (k ^ (lcol&7)). mi-step = +2048 B folds into ds_read immediates.
    const int quad = lane >> 4;
    const int lcol = lane & 15;
    const int plo = ((2 * quad) ^ (lcol & 7)) << 4;
    const int phi = ((2 * quad + 1) ^ (lcol & 7)) << 4;
    const char* aLo = lsA + (wm * 64 + lcol) * 128 + plo;
    const char* aHi = lsA + (wm * 64 + lcol) * 128 + phi;
    const char* bLo = lsB + (wn * 64 + lcol) * 128 + plo;
    const char* bHi = lsB + (wn * 64 + lcol) * 128 + phi;

    floatx4 acc[4][4];
#pragma unroll
    for (int mi = 0; mi < 4; ++mi)
#pragma unroll
        for (int ni = 0; ni < 4; ++ni)
            acc[mi][ni] = (floatx4){0.f, 0.f, 0.f, 0.f};

#pragma unroll 1
    for (int kt = 0; kt < K_TOTAL / 128; ++kt) {            // 16 iterations, NOT unrolled
        __syncthreads();                         // previous iter's frag reads done
#pragma unroll
        for (int j = 0; j < 4; ++j) {
            load16(aPtr + j * 32 * K_TOTAL, lA + j * 4096);
            load16(bPtr + j * 32 * K_TOTAL, lB + j * 4096);
        }
        aPtr += 128;
        bPtr += 128;
        __syncthreads();                         // drains vmcnt -> tiles ready

        // Hold all 4 B-frags (32 VGPRs); stream A-frags one at a time (8 VGPRs).
        int8v bv[4];
#pragma unroll
        for (int i = 0; i < 4; ++i) {
            int4v lo = *(const int4v*)(bLo + i * 2048);
            int4v hi = *(const int4v*)(bHi + i * 2048);
            bv[i] = (int8v){lo.x, lo.y, lo.z, lo.w, hi.x, hi.y, hi.z, hi.w};
        }
#pragma unroll
        for (int mi = 0; mi < 4; ++mi) {
            int4v lo = *(const int4v*)(aLo + mi * 2048);
            int4v hi = *(const int4v*)(aHi + mi * 2048);
            int8v av = (int8v){lo.x, lo.y, lo.z, lo.w, hi.x, hi.y, hi.z, hi.w};
#pragma unroll
            for (int ni = 0; ni < 4; ++ni)
                acc[mi][ni] = __builtin_amdgcn_mfma_scale_f32_16x16x128_f8f6f4(
                    av, bv[ni], acc[mi][ni],
                    0, 0,                         // cbsz=fp8(e4m3), blgp=fp8(e4m3)
                    0, SCALE_E8M0,                // opsel_a, scale_a (2^-9 all bytes)
                    0, SCALE_E8M0);               // opsel_b, scale_b
        }
    }

    // Epilogue: e = exp(sim/TEMP) = exp2(sim * 28.8539); masked min/sum over cols.
    // C/D layout (shape-determined): col = lane&15, row = quad*4 + reg
    const float scale = 28.853900817779268f;     // 20 * log2(e)
#pragma unroll
    for (int mi = 0; mi < 4; ++mi) {
#pragma unroll
        for (int r = 0; r < 4; ++r) {
            const int row_local = wm * 64 + mi * 16 + quad * 4 + r;
            const int lab = lab_m[row_local];
            float minv = __builtin_inff();
            float sumv = 0.f;
#pragma unroll
            for (int ni = 0; ni < 4; ++ni) {
                const int col_local = wn * 64 + ni * 16 + lcol;
                const float e = exp2f(acc[mi][ni][r] * scale);
                const bool pos = (lab_n[col_local] == lab);
                minv = pos ? fminf(minv, e) : minv;
                sumv = pos ? sumv : (sumv + e);
            }
#pragma unroll
            for (int off = 1; off < 16; off <<= 1) {
                minv = fminf(minv, __shfl_xor(minv, off, 16));
                sumv += __shfl_xor(sumv, off, 16);
            }
            if (lcol == 0) {
                // partials laid out [row][part] so reduce_fused reads coalesced
                const long idx = (long)(m0 + row_local) * NPARTS + blockIdx.x * 2 + wn;
                pminp[idx] = minv;
                psump[idx] = sumv;
            }
        }
    }
}

// ---------------------------------------------------------------- row fold + mean
// one wave per row, 512 blocks x 4 waves = 2048 waves. Fuses the old
// final_mean: each block sums its 4 row-losses and atomicAdds (1/M)*partial
// into out[0] (zeroed by cvt_fp8_all; stream order guarantees visibility).
// One device-scope atomic per block (G12), 512 total.
__global__ __launch_bounds__(256) void reduce_fused(
        const float* __restrict__ pminp, const float* __restrict__ psump,
        float* __restrict__ out) {
    const int row  = blockIdx.x * 4 + (threadIdx.x >> 6);
    const int lane = threadIdx.x & 63;
    float m = __builtin_inff();
    float s = 0.f;
#pragma unroll
    for (int k = 0; k < NPARTS / 64; ++k) {
        const long j = (long)row * NPARTS + lane + k * 64;
        m = fminf(m, pminp[j]);
        s += psump[j];
    }
#pragma unroll
    for (int off = 1; off < 64; off <<= 1) {
        m = fminf(m, __shfl_xor(m, off, 64));
        s += __shfl_xor(s, off, 64);
    }
    __shared__ float wloss[4];
    if (lane == 0)
        wloss[threadIdx.x >> 6] = -logf(m / (m + s + 1e-6f) + 1e-6f);
    __syncthreads();
    if (threadIdx.x == 0)
        atomicAdd(out, (wloss[0] + wloss[1] + wloss[2] + wloss[3]) *
                           (1.0f / (float)M_TOTAL));
}

// ---------------------------------------------------------------- launcher
extern "C" void kernel_launch(void* const* d_in, const int* in_sizes, int n_in,
                              void* d_out, int out_size, void* d_ws, size_t ws_size,
                              hipStream_t stream) {
    const float* feats    = (const float*)d_in[0];
    const float* feats_s  = (const float*)d_in[1];
    const int*   labels   = (const int*)d_in[2];
    const int*   labels_s = (const int*)d_in[3];
    float*       out      = (float*)d_out;

    char* ws = (char*)d_ws;
    char*  Af8   = ws;                                    //  4,194,304 B
    char*  Bf8   = ws + 4194304;                          // 33,554,432 B
    float* pminp = (float*)(ws + 37748736);               //  2,097,152 B
    float* psump = (float*)(ws + 39845888);               //  2,097,152 B

    cvt_fp8_all<<<2560, 256, 0, stream>>>((const float4*)feats, (const float4*)feats_s,
                                          (uint32_t*)Af8, (uint32_t*)Bf8, out);

    dim3 grid(N_TOTAL / 128, M_TOTAL / 128);              // 128 x 16
    gemm_lp<<<grid, 256, 0, stream>>>(Af8, Bf8, labels, labels_s, pminp, psump);

    reduce_fused<<<512, 256, 0, stream>>>(pminp, psump, out);
}